// Round 2
// baseline (592.550 us; speedup 1.0000x reference)
//
#include <hip/hip_runtime.h>
#include <cstdint>

#define NCLS 13
#define SMAX 10
#define PTHRESH 0.05f
#define FPS_SEG 8        // blocks per (b,c)
#define FPS_T 1024       // threads per FPS block
#define FPS_PPT 8        // points per thread = 65536 / (FPS_SEG*FPS_T)

// Exact (un-fused) squared distance, matching numpy's ((dx*dx + dy*dy) + dz*dz) in f32.
__device__ __forceinline__ float d2f(float ax, float ay, float az,
                                     float bx, float by, float bz) {
    float dx = ax - bx;
    float dy = ay - by;
    float dz = az - bz;
    return __fadd_rn(__fadd_rn(__fmul_rn(dx, dx), __fmul_rn(dy, dy)), __fmul_rn(dz, dz));
}

// Monotone mapping float -> uint32 (handles +/-inf; no NaNs occur here).
__device__ __forceinline__ unsigned int fmono(float f) {
    unsigned int u = __float_as_uint(f);
    return (u & 0x80000000u) ? ~u : (u | 0x80000000u);
}

// Kernel A: softmax over classes, shifted coords (SoA), per-class valid count + first valid index.
__global__ void k_setup(const float* __restrict__ logits, const float* __restrict__ pts,
                        const float* __restrict__ offs, float* __restrict__ probs,
                        float* __restrict__ sx, float* __restrict__ sy, float* __restrict__ sz,
                        unsigned int* __restrict__ counts, unsigned int* __restrict__ firstv,
                        int N) {
    int b = blockIdx.y;
    int n = blockIdx.x * blockDim.x + threadIdx.x;
    if (n >= N) return;
    size_t bn = (size_t)b * N + n;
    const float* L = logits + bn * NCLS;
    float v[NCLS];
    float mx = -INFINITY;
#pragma unroll
    for (int c = 0; c < NCLS; ++c) { v[c] = L[c]; mx = fmaxf(mx, v[c]); }
    float s = 0.f;
#pragma unroll
    for (int c = 0; c < NCLS; ++c) { v[c] = expf(v[c] - mx); s += v[c]; }
    int lane = threadIdx.x & 63;
    int wave_base = n - lane;
#pragma unroll
    for (int c = 0; c < NCLS; ++c) {
        float p = v[c] / s;
        probs[((size_t)b * NCLS + c) * N + n] = p;
        unsigned long long m = __ballot(p > PTHRESH);
        if (lane == 0 && m) {
            atomicAdd(&counts[b * NCLS + c], (unsigned int)__popcll(m));
            atomicMin(&firstv[b * NCLS + c], (unsigned int)(wave_base + __ffsll(m) - 1));
        }
    }
    float x = pts[bn * 3 + 0] + offs[bn * 3 + 0];
    float y = pts[bn * 3 + 1] + offs[bn * 3 + 1];
    float z = pts[bn * 3 + 2] + offs[bn * 3 + 2];
    sx[bn] = x; sy[bn] = y; sz[bn] = z;
}

// Kernel B: deterministic FPS per (b,c), split over FPS_SEG blocks.
// Coords + mind live in registers. Per step: block argmax -> u64 atomicMax slot ->
// per-bc spin barrier (8 arrivals) -> all blocks read winner. Arithmetic identical to
// the single-block version (fminf(m, d2+add), strict-> first-occurrence argmax).
__global__ __launch_bounds__(FPS_T, 4) void k_fps(
    const float* __restrict__ probs,
    const float* __restrict__ sx, const float* __restrict__ sy, const float* __restrict__ sz,
    const unsigned int* __restrict__ counts, const unsigned int* __restrict__ firstv,
    int* __restrict__ nseeds, float* __restrict__ seedxyz,
    unsigned long long* __restrict__ slots,   // [B*NCLS][SMAX], zeroed
    unsigned int* __restrict__ bars,          // [B*NCLS], zeroed
    int N) {
    int g = blockIdx.x;     // segment
    int c = blockIdx.y;
    int b = blockIdx.z;
    int bc = b * NCLS + c;
    int count = (int)counts[bc];
    int ns = min(SMAX, min(count / 50, count));
    if (g == 0 && threadIdx.x == 0) nseeds[bc] = ns;
    if (ns == 0) return;   // whole bc-group exits together; per-bc barrier unaffected

    const float* px = sx + (size_t)b * N;
    const float* py = sy + (size_t)b * N;
    const float* pz = sz + (size_t)b * N;
    const float* pp = probs + (size_t)bc * N;

    int t = threadIdx.x;
    int base = g * (FPS_T * FPS_PPT) + t;

    float X[FPS_PPT], Y[FPS_PPT], Z[FPS_PPT], m[FPS_PPT];
    unsigned int vm = 0;
#pragma unroll
    for (int j = 0; j < FPS_PPT; ++j) {
        int n = base + (j << 10);
        X[j] = px[n]; Y[j] = py[n]; Z[j] = pz[n];
        if (pp[n] > PTHRESH) vm |= (1u << j);
        m[j] = INFINITY;
    }

    // seed 0
    int st = (int)firstv[bc];
    float cx = px[st], cy = py[st], cz = pz[st];
    if (g == 0 && t == 0) {
        float* sd = seedxyz + (size_t)bc * SMAX * 3;
        sd[0] = cx; sd[1] = cy; sd[2] = cz;
    }

    __shared__ unsigned long long s_keys[FPS_T / 64];
    unsigned int barv = 0;

    for (int s = 1; s < ns; ++s) {
        float best = -INFINITY;
        int bidx = 0;
#pragma unroll
        for (int j = 0; j < FPS_PPT; ++j) {
            int n = base + (j << 10);
            float d2 = d2f(X[j], Y[j], Z[j], cx, cy, cz);
            float add = ((vm >> j) & 1u) ? 0.0f : -INFINITY;
            float nm = fminf(m[j], __fadd_rn(d2, add));
            m[j] = nm;
            if (nm > best) { best = nm; bidx = n; }  // strict > keeps smallest index
        }
        unsigned long long key =
            ((unsigned long long)fmono(best) << 32) | (unsigned int)(~(unsigned int)bidx);
        // 64-lane butterfly max
#pragma unroll
        for (int off = 1; off < 64; off <<= 1) {
            unsigned long long ok = __shfl_xor(key, off, 64);
            if (ok > key) key = ok;
        }
        int wv = t >> 6;
        if ((t & 63) == 0) s_keys[wv] = key;
        __syncthreads();
        barv += FPS_SEG;
        if (t == 0) {
            unsigned long long bk = s_keys[0];
#pragma unroll
            for (int w = 1; w < FPS_T / 64; ++w) if (s_keys[w] > bk) bk = s_keys[w];
            atomicMax(&slots[bc * SMAX + s], bk);
            __hip_atomic_fetch_add(&bars[bc], 1u, __ATOMIC_ACQ_REL, __HIP_MEMORY_SCOPE_AGENT);
            while (__hip_atomic_load(&bars[bc], __ATOMIC_ACQUIRE, __HIP_MEMORY_SCOPE_AGENT) < barv)
                __builtin_amdgcn_s_sleep(2);
        }
        __syncthreads();
        unsigned long long wk =
            __hip_atomic_load(&slots[bc * SMAX + s], __ATOMIC_ACQUIRE, __HIP_MEMORY_SCOPE_AGENT);
        int widx = (int)(~(unsigned int)wk);
        cx = px[widx]; cy = py[widx]; cz = pz[widx];
        if (g == 0 && t == 0) {
            float* sd = seedxyz + ((size_t)bc * SMAX + s) * 3;
            sd[0] = cx; sd[1] = cy; sd[2] = cz;
        }
        __syncthreads();
    }
}

// Kernel C: per point: Gaussian soft assignment per class, then softmax over K=130 instance
// rows. Fast exp/div on continuous paths only; invalid classes contribute exp(0)=1 exactly.
__global__ void k_out(const float* __restrict__ probs,
                      const float* __restrict__ sx, const float* __restrict__ sy,
                      const float* __restrict__ sz,
                      const int* __restrict__ nseeds, const float* __restrict__ seedxyz,
                      float* __restrict__ out, int N) {
    int b = blockIdx.y;
    int n = blockIdx.x * blockDim.x + threadIdx.x;
    __shared__ float S[NCLS * SMAX * 3];
    __shared__ int NSs[NCLS];
    int t = threadIdx.x;
    for (int i = t; i < NCLS * SMAX * 3; i += blockDim.x)
        S[i] = seedxyz[(size_t)b * NCLS * SMAX * 3 + i];
    if (t < NCLS) NSs[t] = nseeds[b * NCLS + t];
    __syncthreads();
    if (n >= N) return;

    size_t bn = (size_t)b * N + n;
    float x = sx[bn], y = sy[bn], z = sz[bn];

    const float kinv = 22.2222222f;   // 1/0.045
    float gd[NCLS];
    float sumexp = 0.f;
#pragma unroll
    for (int c = 0; c < NCLS; ++c) {
        int ns = NSs[c];
        gd[c] = 0.f;
        if (ns == 0) continue;
        float pv = probs[((size_t)b * NCLS + c) * N + n];
        if (pv > PTHRESH) {
            float w[SMAX];
            float sw = 0.f;
#pragma unroll
            for (int s = 0; s < SMAX; ++s) {
                w[s] = 0.f;
                if (s < ns) {
                    const float* sd = &S[(c * SMAX + s) * 3];
                    float d2 = d2f(x, y, z, sd[0], sd[1], sd[2]);
                    w[s] = __expf(-d2 * kinv);
                    sw += w[s];
                }
            }
            float gdv = __fdividef(pv, sw + 1e-8f);
            gd[c] = gdv;
#pragma unroll
            for (int s = 0; s < SMAX; ++s)
                if (s < ns) sumexp += __expf(10.f * w[s] * gdv);
        } else {
            sumexp += (float)ns;   // exp(0)=1 per valid seed, exact
        }
    }

    float inv = __fdividef(1.f, sumexp);
    float* ob = out + (size_t)b * (NCLS * SMAX) * N + n;
#pragma unroll
    for (int c = 0; c < NCLS; ++c) {
        int ns = NSs[c];
        float gdv = gd[c];
#pragma unroll
        for (int s = 0; s < SMAX; ++s) {
            float o = 0.f;
            if (s < ns) {
                if (gdv > 0.f) {
                    const float* sd = &S[(c * SMAX + s) * 3];
                    float d2 = d2f(x, y, z, sd[0], sd[1], sd[2]);
                    float wv = __expf(-d2 * kinv);
                    o = __expf(10.f * wv * gdv) * inv;
                } else {
                    o = inv;
                }
            }
            ob[(size_t)(c * SMAX + s) * N] = o;
        }
    }
}

extern "C" void kernel_launch(void* const* d_in, const int* in_sizes, int n_in,
                              void* d_out, int out_size, void* d_ws, size_t ws_size,
                              hipStream_t stream) {
    const float* logits = (const float*)d_in[0];
    const float* pts    = (const float*)d_in[1];
    const float* offs   = (const float*)d_in[2];
    float* out = (float*)d_out;

    const int B = 2;
    const int BN = in_sizes[0] / NCLS;   // B*N
    const int N = BN / B;                // 65536

    // Workspace layout
    char* w = (char*)d_ws;
    size_t off = 0;
    auto take = [&](size_t bytes) -> void* {
        void* p = w + off;
        off = (off + bytes + 255) & ~(size_t)255;
        return p;
    };
    float* probs   = (float*)take((size_t)B * NCLS * N * sizeof(float));
    float* sx      = (float*)take((size_t)B * N * sizeof(float));
    float* sy      = (float*)take((size_t)B * N * sizeof(float));
    float* sz      = (float*)take((size_t)B * N * sizeof(float));
    float* seedxyz = (float*)take((size_t)B * NCLS * SMAX * 3 * sizeof(float));
    unsigned int* counts = (unsigned int*)take(B * NCLS * sizeof(unsigned int));
    unsigned int* firstv = (unsigned int*)take(B * NCLS * sizeof(unsigned int));
    int* nseeds          = (int*)take(B * NCLS * sizeof(int));
    unsigned long long* slots = (unsigned long long*)take(B * NCLS * SMAX * sizeof(unsigned long long));
    unsigned int* bars   = (unsigned int*)take(B * NCLS * sizeof(unsigned int));

    hipMemsetAsync(counts, 0x00, B * NCLS * sizeof(unsigned int), stream);
    hipMemsetAsync(firstv, 0xFF, B * NCLS * sizeof(unsigned int), stream);
    hipMemsetAsync(slots, 0x00, B * NCLS * SMAX * sizeof(unsigned long long), stream);
    hipMemsetAsync(bars, 0x00, B * NCLS * sizeof(unsigned int), stream);

    dim3 gA((N + 255) / 256, B);
    k_setup<<<gA, 256, 0, stream>>>(logits, pts, offs, probs, sx, sy, sz, counts, firstv, N);

    dim3 gB(FPS_SEG, NCLS, B);
    k_fps<<<gB, FPS_T, 0, stream>>>(probs, sx, sy, sz, counts, firstv, nseeds, seedxyz,
                                    slots, bars, N);

    dim3 gC((N + 255) / 256, B);
    k_out<<<gC, 256, 0, stream>>>(probs, sx, sy, sz, nseeds, seedxyz, out, N);
}

// Round 3
// 108.030 us; speedup vs baseline: 5.4850x; 5.4850x over previous
//
#include <hip/hip_runtime.h>
#include <cstdint>

#define NCLS 13
#define SMAX 10
#define PTHRESH 0.05f
#define FPS_SEG 8        // blocks per (b,c)
#define FPS_T 1024       // threads per FPS block
#define FPS_PPT 8        // points per thread = 65536 / (FPS_SEG*FPS_T)

// Exact (un-fused) squared distance, matching numpy's ((dx*dx + dy*dy) + dz*dz) in f32.
__device__ __forceinline__ float d2f(float ax, float ay, float az,
                                     float bx, float by, float bz) {
    float dx = ax - bx;
    float dy = ay - by;
    float dz = az - bz;
    return __fadd_rn(__fadd_rn(__fmul_rn(dx, dx), __fmul_rn(dy, dy)), __fmul_rn(dz, dz));
}

// Monotone mapping float -> uint32 (handles +/-inf; no NaNs occur here).
// Note: never returns 0 for any non-NaN input, so key==0 means "slot empty".
__device__ __forceinline__ unsigned int fmono(float f) {
    unsigned int u = __float_as_uint(f);
    return (u & 0x80000000u) ? ~u : (u | 0x80000000u);
}

// Kernel A: softmax over classes, shifted coords (SoA), per-class valid count + first valid
// index. Counts/first-index staged in LDS: 13 global atomics per block instead of per-wave.
__global__ void k_setup(const float* __restrict__ logits, const float* __restrict__ pts,
                        const float* __restrict__ offs, float* __restrict__ probs,
                        float* __restrict__ sx, float* __restrict__ sy, float* __restrict__ sz,
                        unsigned int* __restrict__ counts, unsigned int* __restrict__ firstv,
                        int N) {
    int b = blockIdx.y;
    int n = blockIdx.x * blockDim.x + threadIdx.x;
    int t = threadIdx.x;
    __shared__ unsigned int sC[NCLS], sF[NCLS];
    if (t < NCLS) { sC[t] = 0u; sF[t] = 0xFFFFFFFFu; }
    __syncthreads();

    if (n < N) {
        size_t bn = (size_t)b * N + n;
        const float* L = logits + bn * NCLS;
        float v[NCLS];
        float mx = -INFINITY;
#pragma unroll
        for (int c = 0; c < NCLS; ++c) { v[c] = L[c]; mx = fmaxf(mx, v[c]); }
        float s = 0.f;
#pragma unroll
        for (int c = 0; c < NCLS; ++c) { v[c] = expf(v[c] - mx); s += v[c]; }
        int lane = t & 63;
        int wave_base = n - lane;
#pragma unroll
        for (int c = 0; c < NCLS; ++c) {
            float p = v[c] / s;
            probs[((size_t)b * NCLS + c) * N + n] = p;
            unsigned long long m = __ballot(p > PTHRESH);
            if (lane == 0 && m) {
                atomicAdd(&sC[c], (unsigned int)__popcll(m));
                atomicMin(&sF[c], (unsigned int)(wave_base + __ffsll(m) - 1));
            }
        }
        float x = pts[bn * 3 + 0] + offs[bn * 3 + 0];
        float y = pts[bn * 3 + 1] + offs[bn * 3 + 1];
        float z = pts[bn * 3 + 2] + offs[bn * 3 + 2];
        sx[bn] = x; sy[bn] = y; sz[bn] = z;
    }
    __syncthreads();
    if (t < NCLS) {
        if (sC[t]) atomicAdd(&counts[b * NCLS + t], sC[t]);
        if (sF[t] != 0xFFFFFFFFu) atomicMin(&firstv[b * NCLS + t], sF[t]);
    }
}

// Kernel B: deterministic FPS per (b,c), split over FPS_SEG blocks. Coords + mind in
// registers. Per step: block-reduce best key -> release-store to own slot (one 64B line
// per (bc,step), no cross-group sharing) -> wave 0 polls all 8 slots nonzero -> winner.
// The poll IS the barrier (pure forward dataflow; each step has its own slots).
__global__ __launch_bounds__(FPS_T) void k_fps(
    const float* __restrict__ probs,
    const float* __restrict__ sx, const float* __restrict__ sy, const float* __restrict__ sz,
    const unsigned int* __restrict__ counts, const unsigned int* __restrict__ firstv,
    int* __restrict__ nseeds, float* __restrict__ seedxyz,
    unsigned long long* __restrict__ slots,   // [B*NCLS][SMAX][FPS_SEG], zeroed
    int N) {
    int g = blockIdx.x;     // segment
    int c = blockIdx.y;
    int b = blockIdx.z;
    int bc = b * NCLS + c;
    int count = (int)counts[bc];
    int ns = min(SMAX, min(count / 50, count));
    if (g == 0 && threadIdx.x == 0) nseeds[bc] = ns;
    if (ns == 0) return;

    const float* px = sx + (size_t)b * N;
    const float* py = sy + (size_t)b * N;
    const float* pz = sz + (size_t)b * N;
    const float* pp = probs + (size_t)bc * N;

    int t = threadIdx.x;
    int base = g * (FPS_T * FPS_PPT) + t;

    float X[FPS_PPT], Y[FPS_PPT], Z[FPS_PPT], m[FPS_PPT];
    unsigned int vm = 0;
#pragma unroll
    for (int j = 0; j < FPS_PPT; ++j) {
        int n = base + (j << 10);
        X[j] = px[n]; Y[j] = py[n]; Z[j] = pz[n];
        if (pp[n] > PTHRESH) vm |= (1u << j);
        m[j] = INFINITY;
    }

    // seed 0
    int st = (int)firstv[bc];
    float cx = px[st], cy = py[st], cz = pz[st];
    if (g == 0 && t == 0) {
        float* sd = seedxyz + (size_t)bc * SMAX * 3;
        sd[0] = cx; sd[1] = cy; sd[2] = cz;
    }

    __shared__ unsigned long long s_keys[FPS_T / 64];
    __shared__ unsigned long long s_win;

    for (int s = 1; s < ns; ++s) {
        float best = -INFINITY;
        int bidx = 0;
#pragma unroll
        for (int j = 0; j < FPS_PPT; ++j) {
            int n = base + (j << 10);
            float d2 = d2f(X[j], Y[j], Z[j], cx, cy, cz);
            float add = ((vm >> j) & 1u) ? 0.0f : -INFINITY;
            float nm = fminf(m[j], __fadd_rn(d2, add));
            m[j] = nm;
            if (nm > best) { best = nm; bidx = n; }  // strict > keeps smallest index
        }
        unsigned long long key =
            ((unsigned long long)fmono(best) << 32) | (unsigned int)(~(unsigned int)bidx);
        // 64-lane butterfly max
#pragma unroll
        for (int off = 1; off < 64; off <<= 1) {
            unsigned long long ok = __shfl_xor(key, off, 64);
            if (ok > key) key = ok;
        }
        if ((t & 63) == 0) s_keys[t >> 6] = key;
        __syncthreads();

        if (t < 64) {   // wave 0: block-reduce, publish, poll, resolve winner
            unsigned long long bk = (t < FPS_T / 64) ? s_keys[t] : 0ULL;
#pragma unroll
            for (int off = 1; off < FPS_T / 64; off <<= 1) {
                unsigned long long ok = __shfl_xor(bk, off, FPS_T / 64);
                if (ok > bk) bk = ok;
            }
            unsigned long long* sl = slots + ((size_t)bc * SMAX + s) * FPS_SEG;
            if (t == 0)
                __hip_atomic_store(&sl[g], bk, __ATOMIC_RELEASE, __HIP_MEMORY_SCOPE_AGENT);
            unsigned long long wkey = 0ULL;
            while (true) {
                if (t < FPS_SEG && wkey == 0ULL)
                    wkey = __hip_atomic_load(&sl[t], __ATOMIC_ACQUIRE,
                                             __HIP_MEMORY_SCOPE_AGENT);
                if (__all(wkey != 0ULL || t >= FPS_SEG)) break;
                __builtin_amdgcn_s_sleep(1);
            }
#pragma unroll
            for (int off = 1; off < FPS_SEG; off <<= 1) {
                unsigned long long ok = __shfl_xor(wkey, off, FPS_SEG);
                if (ok > wkey) wkey = ok;
            }
            if (t == 0) s_win = wkey;
        }
        __syncthreads();

        int widx = (int)(~(unsigned int)s_win);
        cx = px[widx]; cy = py[widx]; cz = pz[widx];
        if (g == 0 && t == 0) {
            float* sd = seedxyz + ((size_t)bc * SMAX + s) * 3;
            sd[0] = cx; sd[1] = cy; sd[2] = cz;
        }
    }
}

// Kernel C: per point: Gaussian soft assignment per class, then softmax over K=130 instance
// rows. Fast exp/div on continuous paths only; invalid classes contribute exp(0)=1 exactly.
__global__ void k_out(const float* __restrict__ probs,
                      const float* __restrict__ sx, const float* __restrict__ sy,
                      const float* __restrict__ sz,
                      const int* __restrict__ nseeds, const float* __restrict__ seedxyz,
                      float* __restrict__ out, int N) {
    int b = blockIdx.y;
    int n = blockIdx.x * blockDim.x + threadIdx.x;
    __shared__ float S[NCLS * SMAX * 3];
    __shared__ int NSs[NCLS];
    int t = threadIdx.x;
    for (int i = t; i < NCLS * SMAX * 3; i += blockDim.x)
        S[i] = seedxyz[(size_t)b * NCLS * SMAX * 3 + i];
    if (t < NCLS) NSs[t] = nseeds[b * NCLS + t];
    __syncthreads();
    if (n >= N) return;

    size_t bn = (size_t)b * N + n;
    float x = sx[bn], y = sy[bn], z = sz[bn];

    const float kinv = 22.2222222f;   // 1/0.045
    float gd[NCLS];
    float sumexp = 0.f;
#pragma unroll
    for (int c = 0; c < NCLS; ++c) {
        int ns = NSs[c];
        gd[c] = 0.f;
        if (ns == 0) continue;
        float pv = probs[((size_t)b * NCLS + c) * N + n];
        if (pv > PTHRESH) {
            float w[SMAX];
            float sw = 0.f;
#pragma unroll
            for (int s = 0; s < SMAX; ++s) {
                w[s] = 0.f;
                if (s < ns) {
                    const float* sd = &S[(c * SMAX + s) * 3];
                    float d2 = d2f(x, y, z, sd[0], sd[1], sd[2]);
                    w[s] = __expf(-d2 * kinv);
                    sw += w[s];
                }
            }
            float gdv = __fdividef(pv, sw + 1e-8f);
            gd[c] = gdv;
#pragma unroll
            for (int s = 0; s < SMAX; ++s)
                if (s < ns) sumexp += __expf(10.f * w[s] * gdv);
        } else {
            sumexp += (float)ns;   // exp(0)=1 per valid seed, exact
        }
    }

    float inv = __fdividef(1.f, sumexp);
    float* ob = out + (size_t)b * (NCLS * SMAX) * N + n;
#pragma unroll
    for (int c = 0; c < NCLS; ++c) {
        int ns = NSs[c];
        float gdv = gd[c];
#pragma unroll
        for (int s = 0; s < SMAX; ++s) {
            float o = 0.f;
            if (s < ns) {
                if (gdv > 0.f) {
                    const float* sd = &S[(c * SMAX + s) * 3];
                    float d2 = d2f(x, y, z, sd[0], sd[1], sd[2]);
                    float wv = __expf(-d2 * kinv);
                    o = __expf(10.f * wv * gdv) * inv;
                } else {
                    o = inv;
                }
            }
            ob[(size_t)(c * SMAX + s) * N] = o;
        }
    }
}

extern "C" void kernel_launch(void* const* d_in, const int* in_sizes, int n_in,
                              void* d_out, int out_size, void* d_ws, size_t ws_size,
                              hipStream_t stream) {
    const float* logits = (const float*)d_in[0];
    const float* pts    = (const float*)d_in[1];
    const float* offs   = (const float*)d_in[2];
    float* out = (float*)d_out;

    const int B = 2;
    const int BN = in_sizes[0] / NCLS;   // B*N
    const int N = BN / B;                // 65536

    // Workspace layout
    char* w = (char*)d_ws;
    size_t off = 0;
    auto take = [&](size_t bytes) -> void* {
        void* p = w + off;
        off = (off + bytes + 255) & ~(size_t)255;
        return p;
    };
    float* probs   = (float*)take((size_t)B * NCLS * N * sizeof(float));
    float* sx      = (float*)take((size_t)B * N * sizeof(float));
    float* sy      = (float*)take((size_t)B * N * sizeof(float));
    float* sz      = (float*)take((size_t)B * N * sizeof(float));
    float* seedxyz = (float*)take((size_t)B * NCLS * SMAX * 3 * sizeof(float));
    unsigned int* counts = (unsigned int*)take(B * NCLS * sizeof(unsigned int));
    unsigned int* firstv = (unsigned int*)take(B * NCLS * sizeof(unsigned int));
    int* nseeds          = (int*)take(B * NCLS * sizeof(int));
    unsigned long long* slots =
        (unsigned long long*)take((size_t)B * NCLS * SMAX * FPS_SEG * sizeof(unsigned long long));

    hipMemsetAsync(counts, 0x00, B * NCLS * sizeof(unsigned int), stream);
    hipMemsetAsync(firstv, 0xFF, B * NCLS * sizeof(unsigned int), stream);
    hipMemsetAsync(slots, 0x00, (size_t)B * NCLS * SMAX * FPS_SEG * sizeof(unsigned long long),
                   stream);

    dim3 gA((N + 255) / 256, B);
    k_setup<<<gA, 256, 0, stream>>>(logits, pts, offs, probs, sx, sy, sz, counts, firstv, N);

    dim3 gB(FPS_SEG, NCLS, B);
    k_fps<<<gB, FPS_T, 0, stream>>>(probs, sx, sy, sz, counts, firstv, nseeds, seedxyz,
                                    slots, N);

    dim3 gC((N + 255) / 256, B);
    k_out<<<gC, 256, 0, stream>>>(probs, sx, sy, sz, nseeds, seedxyz, out, N);
}

// Round 4
// 90.195 us; speedup vs baseline: 6.5696x; 1.1977x over previous
//
#include <hip/hip_runtime.h>
#include <cstdint>

#define NCLS 13
#define SMAX 10
#define PTHRESH 0.05f
#define FPS_SEG 8        // blocks per (b,c)
#define FPS_T 512        // threads per FPS block (8 waves)
#define FPS_PPT 16       // points per thread: 8*512*16 = 65536
#define NSLOT 64         // publisher waves per (b,c) = FPS_SEG * FPS_T/64
#define GABLK 256        // k_setup blocks per batch (N/256)
#define BB 2             // batch
#define SLOT_DWORDS (BB * NCLS * SMAX * NSLOT * 2)

// Exact (un-fused) squared distance, matching numpy's ((dx*dx + dy*dy) + dz*dz) in f32.
__device__ __forceinline__ float d2f(float ax, float ay, float az,
                                     float bx, float by, float bz) {
    float dx = ax - bx;
    float dy = ay - by;
    float dz = az - bz;
    return __fadd_rn(__fadd_rn(__fmul_rn(dx, dx), __fmul_rn(dy, dy)), __fmul_rn(dz, dz));
}

// Monotone mapping float -> uint32. Never 0 for non-NaN input => key==0 means "empty".
__device__ __forceinline__ unsigned int fmono(float f) {
    unsigned int u = __float_as_uint(f);
    return (u & 0x80000000u) ? ~u : (u | 0x80000000u);
}

// Kernel A: class softmax, shifted coords (SoA), PER-BLOCK partial counts/first-index
// (full overwrite -> no zero-init, no global atomics), plus zeroing the FPS slots.
__global__ void k_setup(const float* __restrict__ logits, const float* __restrict__ pts,
                        const float* __restrict__ offs, float* __restrict__ probs,
                        float* __restrict__ sx, float* __restrict__ sy, float* __restrict__ sz,
                        unsigned int* __restrict__ pcnt, unsigned int* __restrict__ pfst,
                        unsigned int* __restrict__ slots32, int N) {
    int b = blockIdx.y;
    int n = blockIdx.x * blockDim.x + threadIdx.x;
    int t = threadIdx.x;
    __shared__ unsigned int sC[NCLS], sF[NCLS];
    if (t < NCLS) { sC[t] = 0u; sF[t] = 0xFFFFFFFFu; }
    __syncthreads();

    // zero FPS slots (every call: graph replays leave stale nonzero keys behind)
    if (b == 0) {
        unsigned int i = blockIdx.x * blockDim.x + t;
        if (i < SLOT_DWORDS) slots32[i] = 0u;
    }

    if (n < N) {
        size_t bn = (size_t)b * N + n;
        const float* L = logits + bn * NCLS;
        float v[NCLS];
        float mx = -INFINITY;
#pragma unroll
        for (int c = 0; c < NCLS; ++c) { v[c] = L[c]; mx = fmaxf(mx, v[c]); }
        float s = 0.f;
#pragma unroll
        for (int c = 0; c < NCLS; ++c) { v[c] = expf(v[c] - mx); s += v[c]; }
        int lane = t & 63;
        int wave_base = n - lane;
#pragma unroll
        for (int c = 0; c < NCLS; ++c) {
            float p = v[c] / s;
            probs[((size_t)b * NCLS + c) * N + n] = p;
            unsigned long long m = __ballot(p > PTHRESH);
            if (lane == 0 && m) {
                atomicAdd(&sC[c], (unsigned int)__popcll(m));
                atomicMin(&sF[c], (unsigned int)(wave_base + __ffsll(m) - 1));
            }
        }
        float x = pts[bn * 3 + 0] + offs[bn * 3 + 0];
        float y = pts[bn * 3 + 1] + offs[bn * 3 + 1];
        float z = pts[bn * 3 + 2] + offs[bn * 3 + 2];
        sx[bn] = x; sy[bn] = y; sz[bn] = z;
    }
    __syncthreads();
    if (t < NCLS) {
        pcnt[(b * NCLS + t) * GABLK + blockIdx.x] = sC[t];
        pfst[(b * NCLS + t) * GABLK + blockIdx.x] = sF[t];
    }
}

// Kernel B: deterministic FPS, wave-autonomous. 8 blocks x 8 waves per (b,c) = 64
// publisher waves; slots per (bc,step) = 64 u64 (one per lane of the polling wave).
// Per step: thread partial argmax -> 64-lane butterfly -> lane0 relaxed-store own slot
// -> every lane relaxed-polls its slot (no buffer_inv) -> butterfly max = winner.
// No __syncthreads, no LDS, no fences: the u64 key is pure value communication.
__global__ __launch_bounds__(FPS_T) void k_fps(
    const float* __restrict__ probs,
    const float* __restrict__ sx, const float* __restrict__ sy, const float* __restrict__ sz,
    const unsigned int* __restrict__ pcnt, const unsigned int* __restrict__ pfst,
    int* __restrict__ nseeds, float* __restrict__ seedxyz,
    unsigned long long* __restrict__ slots, int N) {
    int g = blockIdx.x;
    int c = blockIdx.y;
    int b = blockIdx.z;
    int bc = b * NCLS + c;
    int t = threadIdx.x, lane = t & 63, w = t >> 6;

    // Reduce per-block partials (each wave redundantly; identical ops -> identical result)
    const unsigned int* pc = pcnt + (size_t)bc * GABLK;
    const unsigned int* pf = pfst + (size_t)bc * GABLK;
    uint4 c4 = *(const uint4*)(pc + lane * 4);
    uint4 f4 = *(const uint4*)(pf + lane * 4);
    unsigned int cnt = c4.x + c4.y + c4.z + c4.w;
    unsigned int fst = min(min(f4.x, f4.y), min(f4.z, f4.w));
#pragma unroll
    for (int off = 1; off < 64; off <<= 1) {
        cnt += __shfl_xor(cnt, off, 64);
        fst = min(fst, __shfl_xor(fst, off, 64));
    }
    int ns = min(SMAX, min((int)cnt / 50, (int)cnt));
    if (g == 0 && t == 0) nseeds[bc] = ns;
    if (ns == 0) return;

    const float* px = sx + (size_t)b * N;
    const float* py = sy + (size_t)b * N;
    const float* pz = sz + (size_t)b * N;
    const float* pp = probs + (size_t)bc * N;

    int base = g * (FPS_T * FPS_PPT) + t;
    float X[FPS_PPT], Y[FPS_PPT], Z[FPS_PPT], m[FPS_PPT];
    unsigned int vm = 0;
#pragma unroll
    for (int j = 0; j < FPS_PPT; ++j) {
        int n = base + (j << 9);
        X[j] = px[n]; Y[j] = py[n]; Z[j] = pz[n];
        if (pp[n] > PTHRESH) vm |= (1u << j);
        m[j] = INFINITY;
    }

    int st = (int)fst;
    float cx = px[st], cy = py[st], cz = pz[st];
    if (g == 0 && t == 0) {
        float* sd = seedxyz + (size_t)bc * SMAX * 3;
        sd[0] = cx; sd[1] = cy; sd[2] = cz;
    }

    for (int s = 1; s < ns; ++s) {
        float best = -INFINITY;
        int bidx = 0;
#pragma unroll
        for (int j = 0; j < FPS_PPT; ++j) {   // ascending n => first-occurrence tiebreak
            int n = base + (j << 9);
            float d2 = d2f(X[j], Y[j], Z[j], cx, cy, cz);
            float add = ((vm >> j) & 1u) ? 0.0f : -INFINITY;
            float nm = fminf(m[j], __fadd_rn(d2, add));
            m[j] = nm;
            if (nm > best) { best = nm; bidx = n; }
        }
        unsigned long long key =
            ((unsigned long long)fmono(best) << 32) | (unsigned int)(~(unsigned int)bidx);
#pragma unroll
        for (int off = 1; off < 64; off <<= 1) {
            unsigned long long ok = __shfl_xor(key, off, 64);
            if (ok > key) key = ok;
        }
        unsigned long long* sl = slots + ((size_t)bc * SMAX + s) * NSLOT;
        if (lane == 0)
            __hip_atomic_store(&sl[g * (FPS_T / 64) + w], key,
                               __ATOMIC_RELAXED, __HIP_MEMORY_SCOPE_AGENT);
        asm volatile("" ::: "memory");   // pin publish before poll (no runtime cost)
        unsigned long long k = 0ULL;
        while (true) {
            if (k == 0ULL)
                k = __hip_atomic_load(&sl[lane], __ATOMIC_RELAXED, __HIP_MEMORY_SCOPE_AGENT);
            if (__all(k != 0ULL)) break;
        }
        asm volatile("" ::: "memory");
#pragma unroll
        for (int off = 1; off < 64; off <<= 1) {
            unsigned long long ok = __shfl_xor(k, off, 64);
            if (ok > k) k = ok;
        }
        int widx = (int)(~(unsigned int)k);
        cx = px[widx]; cy = py[widx]; cz = pz[widx];
        if (g == 0 && t == 0) {
            float* sd = seedxyz + ((size_t)bc * SMAX + s) * 3;
            sd[0] = cx; sd[1] = cy; sd[2] = cz;
        }
    }
}

// Kernel C: per point: Gaussian soft assignment per class, then softmax over K=130 instance
// rows. Fast exp/div on continuous paths only; invalid classes contribute exp(0)=1 exactly.
__global__ void k_out(const float* __restrict__ probs,
                      const float* __restrict__ sx, const float* __restrict__ sy,
                      const float* __restrict__ sz,
                      const int* __restrict__ nseeds, const float* __restrict__ seedxyz,
                      float* __restrict__ out, int N) {
    int b = blockIdx.y;
    int n = blockIdx.x * blockDim.x + threadIdx.x;
    __shared__ float S[NCLS * SMAX * 3];
    __shared__ int NSs[NCLS];
    int t = threadIdx.x;
    for (int i = t; i < NCLS * SMAX * 3; i += blockDim.x)
        S[i] = seedxyz[(size_t)b * NCLS * SMAX * 3 + i];
    if (t < NCLS) NSs[t] = nseeds[b * NCLS + t];
    __syncthreads();
    if (n >= N) return;

    size_t bn = (size_t)b * N + n;
    float x = sx[bn], y = sy[bn], z = sz[bn];

    const float kinv = 22.2222222f;   // 1/0.045
    float gd[NCLS];
    float sumexp = 0.f;
#pragma unroll
    for (int c = 0; c < NCLS; ++c) {
        int ns = NSs[c];
        gd[c] = 0.f;
        if (ns == 0) continue;
        float pv = probs[((size_t)b * NCLS + c) * N + n];
        if (pv > PTHRESH) {
            float w[SMAX];
            float sw = 0.f;
#pragma unroll
            for (int s = 0; s < SMAX; ++s) {
                w[s] = 0.f;
                if (s < ns) {
                    const float* sd = &S[(c * SMAX + s) * 3];
                    float d2 = d2f(x, y, z, sd[0], sd[1], sd[2]);
                    w[s] = __expf(-d2 * kinv);
                    sw += w[s];
                }
            }
            float gdv = __fdividef(pv, sw + 1e-8f);
            gd[c] = gdv;
#pragma unroll
            for (int s = 0; s < SMAX; ++s)
                if (s < ns) sumexp += __expf(10.f * w[s] * gdv);
        } else {
            sumexp += (float)ns;   // exp(0)=1 per valid seed, exact
        }
    }

    float inv = __fdividef(1.f, sumexp);
    float* ob = out + (size_t)b * (NCLS * SMAX) * N + n;
#pragma unroll
    for (int c = 0; c < NCLS; ++c) {
        int ns = NSs[c];
        float gdv = gd[c];
#pragma unroll
        for (int s = 0; s < SMAX; ++s) {
            float o = 0.f;
            if (s < ns) {
                if (gdv > 0.f) {
                    const float* sd = &S[(c * SMAX + s) * 3];
                    float d2 = d2f(x, y, z, sd[0], sd[1], sd[2]);
                    float wv = __expf(-d2 * kinv);
                    o = __expf(10.f * wv * gdv) * inv;
                } else {
                    o = inv;
                }
            }
            ob[(size_t)(c * SMAX + s) * N] = o;
        }
    }
}

extern "C" void kernel_launch(void* const* d_in, const int* in_sizes, int n_in,
                              void* d_out, int out_size, void* d_ws, size_t ws_size,
                              hipStream_t stream) {
    const float* logits = (const float*)d_in[0];
    const float* pts    = (const float*)d_in[1];
    const float* offs   = (const float*)d_in[2];
    float* out = (float*)d_out;

    const int B = BB;
    const int BN = in_sizes[0] / NCLS;   // B*N
    const int N = BN / B;                // 65536

    // Workspace layout
    char* w = (char*)d_ws;
    size_t off = 0;
    auto take = [&](size_t bytes) -> void* {
        void* p = w + off;
        off = (off + bytes + 255) & ~(size_t)255;
        return p;
    };
    float* probs   = (float*)take((size_t)B * NCLS * N * sizeof(float));
    float* sx      = (float*)take((size_t)B * N * sizeof(float));
    float* sy      = (float*)take((size_t)B * N * sizeof(float));
    float* sz      = (float*)take((size_t)B * N * sizeof(float));
    float* seedxyz = (float*)take((size_t)B * NCLS * SMAX * 3 * sizeof(float));
    unsigned int* pcnt = (unsigned int*)take((size_t)B * NCLS * GABLK * sizeof(unsigned int));
    unsigned int* pfst = (unsigned int*)take((size_t)B * NCLS * GABLK * sizeof(unsigned int));
    int* nseeds        = (int*)take(B * NCLS * sizeof(int));
    unsigned long long* slots =
        (unsigned long long*)take((size_t)B * NCLS * SMAX * NSLOT * sizeof(unsigned long long));

    dim3 gA((N + 255) / 256, B);   // == (GABLK, B)
    k_setup<<<gA, 256, 0, stream>>>(logits, pts, offs, probs, sx, sy, sz,
                                    pcnt, pfst, (unsigned int*)slots, N);

    dim3 gB(FPS_SEG, NCLS, B);
    k_fps<<<gB, FPS_T, 0, stream>>>(probs, sx, sy, sz, pcnt, pfst, nseeds, seedxyz,
                                    slots, N);

    dim3 gC((N + 255) / 256, B);
    k_out<<<gC, 256, 0, stream>>>(probs, sx, sy, sz, nseeds, seedxyz, out, N);
}